// Round 18
// baseline (326.221 us; speedup 1.0000x reference)
//
#include <hip/hip_runtime.h>

// ResLSTM: B=4096, T=512, H=32.
// R25 = R21 x 4 GROUPS PER BLOCK -> TWO WAVES PER SIMD from INDEPENDENT
//   recurrences.
//   Block = 512 thr = 8 waves = 4 groups of 16 batches; group g = waves
//   {2g, 2g+1} (R21's 2-wave K=32 structure, group-indexed LDS). HW maps
//   wave w -> SIMD w%4, so SIMD s hosts waves s and s+4 = DIFFERENT groups:
//   each fills the other's VALU dependency bubbles and barrier idle.
// WHY (R12..R24 accounting): hand-counted issue ~280 cy/wave-step vs
//   measured busy ~560 -- at 1 wave/SIMD dependent VALU issues at ~4cy/instr
//   (latency-bound); a co-resident wave restores ~2cy. R7 (4 waves/SIMD)
//   ran at 2cy. The 240cy barrier idle is likewise only fillable by a wave
//   from an independent group.
// R24 POST-MORTEM: K=16 split REGRESSED (194.3): MfmaUtil doubled at equal
//   FLOPs -> K=16 occupies the matrix pipe as long as K=32. 4x K=32 is
//   optimal; reverted to R21 tiles.
// History: R7 341. R11 297. R12 dot2 248. R14 230. R16 219 (VALU floor).
//   R18 305. R19 279. R20 197. R21 183.7 (base). R22 338. R23 192.9.
//   R24 194.3 (all reverted).
// Predict: SIMD-step = 2x276 issue + ~80 barrier ~ 630 cy vs R21's 911 ->
//   130-160 us; VALUBusy(CU) 60-75%; MfmaUtil 9-11; absmax EXACTLY
//   0.0009765625. Failure >=180: 8-wave convoy -> R21 is the floor.

static constexpr int T_LEN = 512;
static constexpr int H = 32;

typedef _Float16 h2   __attribute__((ext_vector_type(2)));
typedef __fp16   fp2  __attribute__((ext_vector_type(2)));   // cvt_pkrtz type
typedef _Float16 v8h  __attribute__((ext_vector_type(8)));
typedef float    v4f  __attribute__((ext_vector_type(4)));

// D = A(8 f16) x B(8 f16) + C(4 f32), 16x16x32 f16 MFMA (K=32).
__device__ __forceinline__ v4f MF32(v8h a, v8h b, v4f c) {
#if __has_builtin(__builtin_amdgcn_mfma_f32_16x16x32_f16)
    return __builtin_amdgcn_mfma_f32_16x16x32_f16(a, b, c, 0, 0, 0);
#else
    v4f d = c;
    asm("v_mfma_f32_16x16x32_f16 %0, %1, %2, %0" : "+v"(d) : "v"(a), "v"(b));
    return d;
#endif
}

__device__ __forceinline__ v8h mkB(uint4 w) {
    union { uint4 u; v8h v; } u;
    u.u = w; return u.v;
}

__global__ void
__attribute__((amdgpu_flat_work_group_size(512, 512), amdgpu_waves_per_eu(2, 2)))
reslstm_kernel(const float* __restrict__ x,
               const float* __restrict__ W_ih,
               const float* __restrict__ W_hh,
               const float* __restrict__ b_ih,
               const float* __restrict__ b_hh,
               const float* __restrict__ W_fc,
               const float* __restrict__ b_fc,
               float* __restrict__ out, int B)
{
    // Per-group staging. grp = wv>>1.
    __shared__ float xl[4][16][36];            // x chunk per group
    __shared__ uint2 hx[4][2][4][16][2];       // h exch: [grp][par][q][c][wp]
    __shared__ float osum[4][2][16];

    const int tid  = threadIdx.x;
    const int lane = tid & 63;
    const int wv   = tid >> 6;           // 0..7
    const int grp  = wv >> 1;            // group 0..3 (waves 2g, 2g+1)
    const int wp   = wv & 1;             // 0: units 0-15, 1: units 16-31
    const int c    = lane & 15;          // batch col (0..15)
    const int q    = lane >> 4;          // row quad  (0..3)

    const int wbase = blockIdx.x << 6;   // 64 batches per block
    if (wbase >= B) return;              // block-uniform guard
    const int bbase = wbase + (grp << 4);
    const int bb    = bbase + c;

    constexpr float NL2E  = -1.4426950408889634f;   // -log2(e)
    constexpr float N2L2E = 2.0f * NL2E;

    // A fragments: tile t = 2k + wp (gate k of unit-half wp).
    //   A8[k][m]   = Whh_sc[16t + c][4q + m]      (k-half 0)
    //   A8[k][4+m] = Whh_sc[16t + c][16 + 4q + m] (k-half 1)
    // Prescale: g gate (k==2) by 2*-log2(e), else -log2(e).
    v8h A8[4];
    v4f wih[4], bsb[4];
    #pragma unroll
    for (int k = 0; k < 4; ++k) {
        const int   t  = 2 * k + wp;
        const float sc = (k == 2) ? N2L2E : NL2E;
        const float4 w1 = *reinterpret_cast<const float4*>(
            W_hh + (16 * t + c) * H + 4 * q);
        const float4 w2 = *reinterpret_cast<const float4*>(
            W_hh + (16 * t + c) * H + 16 + 4 * q);
        A8[k][0] = (_Float16)(w1.x * sc); A8[k][1] = (_Float16)(w1.y * sc);
        A8[k][2] = (_Float16)(w1.z * sc); A8[k][3] = (_Float16)(w1.w * sc);
        A8[k][4] = (_Float16)(w2.x * sc); A8[k][5] = (_Float16)(w2.y * sc);
        A8[k][6] = (_Float16)(w2.z * sc); A8[k][7] = (_Float16)(w2.w * sc);
        const int r0 = 16 * t + 4 * q;
        const float4 wi = *reinterpret_cast<const float4*>(W_ih + r0);
        const float4 bi = *reinterpret_cast<const float4*>(b_ih + r0);
        const float4 bh = *reinterpret_cast<const float4*>(b_hh + r0);
        wih[k][0] = wi.x * sc; wih[k][1] = wi.y * sc;
        wih[k][2] = wi.z * sc; wih[k][3] = wi.w * sc;
        bsb[k][0] = (bi.x + bh.x) * sc; bsb[k][1] = (bi.y + bh.y) * sc;
        bsb[k][2] = (bi.z + bh.z) * sc; bsb[k][3] = (bi.w + bh.w) * sc;
    }

    // State: this wave's 4 units (16wp + 4q + m) of its group's batches.
    float cs0 = 0.f, cs1 = 0.f, cs2 = 0.f, cs3 = 0.f;
    float hv0 = 0.f, hv1 = 0.f, hv2 = 0.f, hv3 = 0.f;
    v8h B8 = mkB(uint4{0u, 0u, 0u, 0u});          // h(0) = 0

// Light pins once per chunk (R6 lesson: asm outputs can't be rematerialized
// from memory; R13: placement neutral).
#define PINALL()                                                              \
    asm volatile("" : "+v"(A8[0]), "+v"(A8[1]), "+v"(A8[2]), "+v"(A8[3]));    \
    asm volatile("" : "+v"(wih[0]), "+v"(wih[1]), "+v"(wih[2]), "+v"(wih[3]), \
                      "+v"(bsb[0]), "+v"(bsb[1]), "+v"(bsb[2]), "+v"(bsb[3]))

// R14 exp2 gate math (accums prescaled by -log2(e)):
//   c' = [c*Di*Dg + (1-Eg)*Df] * rcp(Df*Di*Dg);  h = (1-Ec) * rcp(Do*Dc).
#define GSTATE(AI, AF, AG, AO, CC, HH) do {                                   \
    const float Ei = __builtin_amdgcn_exp2f(AI);                              \
    const float Ef = __builtin_amdgcn_exp2f(AF);                              \
    const float Eg = __builtin_amdgcn_exp2f(AG);                              \
    const float Eo = __builtin_amdgcn_exp2f(AO);                              \
    const float Di = 1.0f + Ei, Df = 1.0f + Ef;                               \
    const float Dg = 1.0f + Eg, Do_ = 1.0f + Eo;                              \
    const float P  = Di * Dg;                                                 \
    const float t_ = (1.0f - Eg) * Df;                                        \
    const float u_ = __builtin_fmaf(CC, P, t_);                               \
    const float Rc = __builtin_amdgcn_rcpf(Df * P);                           \
    CC = u_ * Rc;                                                             \
    const float Ec = __builtin_amdgcn_exp2f(CC * N2L2E);                      \
    const float Dc = 1.0f + Ec;                                               \
    const float Rh = __builtin_amdgcn_rcpf(Do_ * Dc);                         \
    HH = (1.0f - Ec) * Rh;                                                    \
} while (0)

// One time step (this wave's half of its group). PAR = parity buffer.
// 4 MFMA K=32 -> 4 GSTATE (h written as b32 ASAP) -> raw barrier (all 8
// waves, symmetric cadence) -> b128 read of both halves.
// Race proof per group as R20/R21: read(t)[p] < own MFMA(t) < write(t+1)
// [1-p] < barrier(t+1) < other wave's write(t+2)[p].
#define STEP(XT, PAR) do {                                                    \
    const float xt = (XT);                                                    \
    v4f acc[4];                                                               \
    _Pragma("unroll")                                                         \
    for (int k = 0; k < 4; ++k) acc[k] = bsb[k] + wih[k] * xt;                \
    _Pragma("unroll")                                                         \
    for (int k = 0; k < 4; ++k) acc[k] = MF32(A8[k], B8, acc[k]);             \
    unsigned int* slot =                                                      \
        reinterpret_cast<unsigned int*>(&hx[grp][PAR][q][c][wp]);             \
    GSTATE(acc[0][0], acc[1][0], acc[2][0], acc[3][0], cs0, hv0);             \
    GSTATE(acc[0][1], acc[1][1], acc[2][1], acc[3][1], cs1, hv1);             \
    slot[0] = __builtin_bit_cast(unsigned int,                                \
                  __builtin_amdgcn_cvt_pkrtz(hv0, hv1));                      \
    GSTATE(acc[0][2], acc[1][2], acc[2][2], acc[3][2], cs2, hv2);             \
    GSTATE(acc[0][3], acc[1][3], acc[2][3], acc[3][3], cs3, hv3);             \
    slot[1] = __builtin_bit_cast(unsigned int,                                \
                  __builtin_amdgcn_cvt_pkrtz(hv2, hv3));                      \
    asm volatile("s_waitcnt lgkmcnt(0)\n\ts_barrier" ::: "memory");           \
    B8 = mkB(*reinterpret_cast<const uint4*>(&hx[grp][PAR][q][c][0]));        \
} while (0)

    // x staging: thread tid stages group sg = tid>>7, row sr, cols scolb..+3.
    const int sg    = tid >> 7;
    const int sr    = (tid >> 3) & 15;
    const int scolb = (tid & 7) << 2;
    const float* xsrc = x + (size_t)(wbase + (sg << 4) + sr) * T_LEN + scolb;
    float4 xA = *reinterpret_cast<const float4*>(xsrc);

    for (int tc = 0; tc < T_LEN / 32; ++tc) {
        PINALL();
        *reinterpret_cast<float4*>(&xl[sg][sr][scolb]) = xA;
        __syncthreads();                  // stage visible to all 8 waves
        if (tc + 1 < T_LEN / 32)
            xA = *reinterpret_cast<const float4*>(xsrc + (tc + 1) * 32);
        const float4* xq4c = reinterpret_cast<const float4*>(&xl[grp][c][0]);
        #pragma unroll 2
        for (int t4 = 0; t4 < 8; ++t4) {
            const float4 xv = xq4c[t4];   // 4 steps of x in regs
            STEP(xv.x, 0);
            STEP(xv.y, 1);
            STEP(xv.z, 0);
            STEP(xv.w, 1);
        }
    }
#undef STEP
#undef GSTATE
#undef PINALL

    // out[bb] = sum_u h[u]*W_fc[u] + b_fc. This wave: units 16wp+4q+m.
    const int u0 = 16 * wp + 4 * q;
    float val = hv0 * W_fc[u0]     + hv1 * W_fc[u0 + 1]
              + hv2 * W_fc[u0 + 2] + hv3 * W_fc[u0 + 3];
    val += __shfl_xor(val, 16);
    val += __shfl_xor(val, 32);
    if (q == 0) osum[grp][wp][c] = val;
    __syncthreads();
    if (wp == 0 && q == 0 && bb < B)
        out[bb] = osum[grp][0][c] + osum[grp][1][c] + b_fc[0];
}

extern "C" void kernel_launch(void* const* d_in, const int* in_sizes, int n_in,
                              void* d_out, int out_size, void* d_ws, size_t ws_size,
                              hipStream_t stream) {
    const float* x    = (const float*)d_in[0];
    const float* W_ih = (const float*)d_in[1];
    const float* W_hh = (const float*)d_in[2];
    const float* b_ih = (const float*)d_in[3];
    const float* b_hh = (const float*)d_in[4];
    const float* W_fc = (const float*)d_in[5];
    const float* b_fc = (const float*)d_in[6];
    float* out = (float*)d_out;
    const int B = in_sizes[0] / T_LEN;        // 4096
    dim3 block(512);                          // 8 waves = 4 groups x 16 batches
    dim3 grid((B + 63) / 64);                 // 64 blocks -> 2 waves/SIMD
    reslstm_kernel<<<grid, block, 0, stream>>>(x, W_ih, W_hh, b_ih, b_hh,
                                               W_fc, b_fc, out, B);
}

// Round 19
// 278.832 us; speedup vs baseline: 1.1700x; 1.1700x over previous
//
#include <hip/hip_runtime.h>

// ResLSTM: B=4096, T=512, H=32.
// R26 = R21 (2 waves, 16 batches, K=32 MFMA recurrence) with the s_barrier
//   exchange replaced by DATA-FLOW FLAG SYNC.
//   Per step: 4 MFMA K=32 -> 4 GSTATE -> write own h (2x b32) -> write
//   flag=ts (b32; DS ops of a wave complete IN ORDER -> flag implies data)
//   -> poll partner flag==ts (volatile b32 + __all) -> fence -> b128 read
//   of both halves -> B8. No lgkmcnt(0) drain, no s_barrier, no convoy.
//   Deadlock-free: wave's step-t write precedes its step-t poll; mutual
//   progress by induction. Clobber-safe: my rewrite of buf[p] at step t+2
//   is ordered after partner's read of buf[p] at step t via my poll of
//   partner's flag(t+1) (same mutual-dependency argument as R21).
// R25 POST-MORTEM: 64 blocks -> only 64 CUs busy (blocks don't split);
//   block-wide barrier locksteps 8 symmetric waves -> aligned bubbles, no
//   filling; 267.9 us. With 256 groups total, >1 group/CU necessarily
//   idles CUs -> R21 config is optimal; only its sync chain is reducible.
// History: R7 341. R11 297. R12 dot2 248. R14 230. R16 219 (VALU floor).
//   R18 305. R19 279. R20 197. R21 183.7 (base). R22 338. R23 192.9.
//   R24 194.3. R25 267.9 (all reverted).
// Predict: -80-120 cy/step -> steady 160-170 us; VALUBusy(CU) 33-37;
//   MfmaUtil 3.6-4.0; absmax EXACTLY 0.0009765625. Failure >=180: R21
//   structure at floor -> declare.

static constexpr int T_LEN = 512;
static constexpr int H = 32;

typedef _Float16 h2   __attribute__((ext_vector_type(2)));
typedef __fp16   fp2  __attribute__((ext_vector_type(2)));   // cvt_pkrtz type
typedef _Float16 v8h  __attribute__((ext_vector_type(8)));
typedef float    v4f  __attribute__((ext_vector_type(4)));

// D = A(8 f16) x B(8 f16) + C(4 f32), 16x16x32 f16 MFMA (K=32).
__device__ __forceinline__ v4f MF32(v8h a, v8h b, v4f c) {
#if __has_builtin(__builtin_amdgcn_mfma_f32_16x16x32_f16)
    return __builtin_amdgcn_mfma_f32_16x16x32_f16(a, b, c, 0, 0, 0);
#else
    v4f d = c;
    asm("v_mfma_f32_16x16x32_f16 %0, %1, %2, %0" : "+v"(d) : "v"(a), "v"(b));
    return d;
#endif
}

__device__ __forceinline__ v8h mkB(uint4 w) {
    union { uint4 u; v8h v; } u;
    u.u = w; return u.v;
}

__global__ void
__attribute__((amdgpu_flat_work_group_size(128, 128), amdgpu_waves_per_eu(1, 1)))
reslstm_kernel(const float* __restrict__ x,
               const float* __restrict__ W_ih,
               const float* __restrict__ W_hh,
               const float* __restrict__ b_ih,
               const float* __restrict__ b_hh,
               const float* __restrict__ W_fc,
               const float* __restrict__ b_fc,
               float* __restrict__ out, int B)
{
    // x chunk: [batch-col][t], pad 36.
    __shared__ float xl[16][36];
    // h exchange, parity-buffered: [buf][q][c][wave] 8B slots.
    __shared__ uint2 hx[2][4][16][2];
    // step-counter flags, parity-buffered per slot.
    __shared__ unsigned hfl[2][4][16][2];
    __shared__ float osum[2][16];

    const int tid  = threadIdx.x;
    const int lane = tid & 63;
    const int wv   = tid >> 6;           // wave 0: units 0-15, wave 1: 16-31
    const int c    = lane & 15;          // batch col (0..15)
    const int q    = lane >> 4;          // row quad  (0..3)

    const int wbase = blockIdx.x << 4;   // 16 batches per block
    if (wbase >= B) return;              // block-uniform guard
    const int bb = wbase + c;

    constexpr float NL2E  = -1.4426950408889634f;   // -log2(e)
    constexpr float N2L2E = 2.0f * NL2E;

    // A fragments: tile t = 2k + wv (gate k of unit-half wv).
    //   A8[k][m]   = Whh_sc[16t + c][4q + m]      (k-half 0)
    //   A8[k][4+m] = Whh_sc[16t + c][16 + 4q + m] (k-half 1)
    // Prescale: g gate (k==2) by 2*-log2(e), else -log2(e).
    v8h A8[4];
    v4f wih[4], bsb[4];
    #pragma unroll
    for (int k = 0; k < 4; ++k) {
        const int   t  = 2 * k + wv;
        const float sc = (k == 2) ? N2L2E : NL2E;
        const float4 w1 = *reinterpret_cast<const float4*>(
            W_hh + (16 * t + c) * H + 4 * q);
        const float4 w2 = *reinterpret_cast<const float4*>(
            W_hh + (16 * t + c) * H + 16 + 4 * q);
        A8[k][0] = (_Float16)(w1.x * sc); A8[k][1] = (_Float16)(w1.y * sc);
        A8[k][2] = (_Float16)(w1.z * sc); A8[k][3] = (_Float16)(w1.w * sc);
        A8[k][4] = (_Float16)(w2.x * sc); A8[k][5] = (_Float16)(w2.y * sc);
        A8[k][6] = (_Float16)(w2.z * sc); A8[k][7] = (_Float16)(w2.w * sc);
        const int r0 = 16 * t + 4 * q;
        const float4 wi = *reinterpret_cast<const float4*>(W_ih + r0);
        const float4 bi = *reinterpret_cast<const float4*>(b_ih + r0);
        const float4 bh = *reinterpret_cast<const float4*>(b_hh + r0);
        wih[k][0] = wi.x * sc; wih[k][1] = wi.y * sc;
        wih[k][2] = wi.z * sc; wih[k][3] = wi.w * sc;
        bsb[k][0] = (bi.x + bh.x) * sc; bsb[k][1] = (bi.y + bh.y) * sc;
        bsb[k][2] = (bi.z + bh.z) * sc; bsb[k][3] = (bi.w + bh.w) * sc;
    }

    // State: this wave's 4 units (16wv + 4q + m).
    float cs0 = 0.f, cs1 = 0.f, cs2 = 0.f, cs3 = 0.f;
    float hv0 = 0.f, hv1 = 0.f, hv2 = 0.f, hv3 = 0.f;
    v8h B8 = mkB(uint4{0u, 0u, 0u, 0u});          // h(0) = 0 (in regs)

    // Flag init: 0 never equals any step value ts>=1. Visible after the
    // first __syncthreads below.
    hfl[0][q][c][wv] = 0u;
    hfl[1][q][c][wv] = 0u;

    unsigned ts = 1;                              // step counter 1..512

// Light pins once per chunk (R6 lesson: asm outputs can't be rematerialized
// from memory; R13: placement neutral).
#define PINALL()                                                              \
    asm volatile("" : "+v"(A8[0]), "+v"(A8[1]), "+v"(A8[2]), "+v"(A8[3]));    \
    asm volatile("" : "+v"(wih[0]), "+v"(wih[1]), "+v"(wih[2]), "+v"(wih[3]), \
                      "+v"(bsb[0]), "+v"(bsb[1]), "+v"(bsb[2]), "+v"(bsb[3]))

// R14 exp2 gate math (accums prescaled by -log2(e)):
//   c' = [c*Di*Dg + (1-Eg)*Df] * rcp(Df*Di*Dg);  h = (1-Ec) * rcp(Do*Dc).
#define GSTATE(AI, AF, AG, AO, CC, HH) do {                                   \
    const float Ei = __builtin_amdgcn_exp2f(AI);                              \
    const float Ef = __builtin_amdgcn_exp2f(AF);                              \
    const float Eg = __builtin_amdgcn_exp2f(AG);                              \
    const float Eo = __builtin_amdgcn_exp2f(AO);                              \
    const float Di = 1.0f + Ei, Df = 1.0f + Ef;                               \
    const float Dg = 1.0f + Eg, Do_ = 1.0f + Eo;                              \
    const float P  = Di * Dg;                                                 \
    const float t_ = (1.0f - Eg) * Df;                                        \
    const float u_ = __builtin_fmaf(CC, P, t_);                               \
    const float Rc = __builtin_amdgcn_rcpf(Df * P);                           \
    CC = u_ * Rc;                                                             \
    const float Ec = __builtin_amdgcn_exp2f(CC * N2L2E);                      \
    const float Dc = 1.0f + Ec;                                               \
    const float Rh = __builtin_amdgcn_rcpf(Do_ * Dc);                         \
    HH = (1.0f - Ec) * Rh;                                                    \
} while (0)

// One time step. PAR = parity buffer (= ts&1 pattern by construction).
// 4 MFMA -> 4 GSTATE (h written as b32 ASAP) -> flag=ts -> poll partner
// flag==ts -> fence -> b128 read of both halves -> B8 for next step.
#define STEP(XT, PAR) do {                                                    \
    const float xt = (XT);                                                    \
    v4f acc[4];                                                               \
    _Pragma("unroll")                                                         \
    for (int k = 0; k < 4; ++k) acc[k] = bsb[k] + wih[k] * xt;                \
    _Pragma("unroll")                                                         \
    for (int k = 0; k < 4; ++k) acc[k] = MF32(A8[k], B8, acc[k]);             \
    unsigned int* slot =                                                      \
        reinterpret_cast<unsigned int*>(&hx[PAR][q][c][wv]);                  \
    GSTATE(acc[0][0], acc[1][0], acc[2][0], acc[3][0], cs0, hv0);             \
    GSTATE(acc[0][1], acc[1][1], acc[2][1], acc[3][1], cs1, hv1);             \
    slot[0] = __builtin_bit_cast(unsigned int,                                \
                  __builtin_amdgcn_cvt_pkrtz(hv0, hv1));                      \
    GSTATE(acc[0][2], acc[1][2], acc[2][2], acc[3][2], cs2, hv2);             \
    GSTATE(acc[0][3], acc[1][3], acc[2][3], acc[3][3], cs3, hv3);             \
    slot[1] = __builtin_bit_cast(unsigned int,                                \
                  __builtin_amdgcn_cvt_pkrtz(hv2, hv3));                      \
    hfl[PAR][q][c][wv] = ts;           /* in-order DS: data before flag */    \
    {                                                                         \
        volatile const unsigned* pf = &hfl[PAR][q][c][wv ^ 1];                \
        while (!__all(*pf == ts)) { }                                         \
    }                                                                         \
    asm volatile("" ::: "memory");     /* pin the read below the poll */      \
    B8 = mkB(*reinterpret_cast<const uint4*>(&hx[PAR][q][c][0]));             \
    ++ts;                                                                     \
} while (0)

    // x staging: thread tid owns row r=tid>>3, cols colb..colb+3 of chunk.
    const int r    = tid >> 3;
    const int colb = (tid & 7) << 2;
    const float* xsrc = x + (size_t)(wbase + r) * T_LEN + colb;
    float4 xA = *reinterpret_cast<const float4*>(xsrc);

    for (int tc = 0; tc < T_LEN / 32; ++tc) {
        PINALL();
        *reinterpret_cast<float4*>(&xl[r][colb]) = xA;
        __syncthreads();                  // stage (and flag init) visible
        if (tc + 1 < T_LEN / 32)
            xA = *reinterpret_cast<const float4*>(xsrc + (tc + 1) * 32);
        const float4* xq4c = reinterpret_cast<const float4*>(&xl[c][0]);
        #pragma unroll 2
        for (int t4 = 0; t4 < 8; ++t4) {
            const float4 xv = xq4c[t4];   // 4 steps of x in regs
            STEP(xv.x, 1);                // ts odd -> buf[1] first
            STEP(xv.y, 0);
            STEP(xv.z, 1);
            STEP(xv.w, 0);
        }
    }
#undef STEP
#undef GSTATE
#undef PINALL

    // out[bb] = sum_u h[u]*W_fc[u] + b_fc. This wave: units 16wv+4q+m.
    const int u0 = 16 * wv + 4 * q;
    float val = hv0 * W_fc[u0]     + hv1 * W_fc[u0 + 1]
              + hv2 * W_fc[u0 + 2] + hv3 * W_fc[u0 + 3];
    val += __shfl_xor(val, 16);
    val += __shfl_xor(val, 32);
    if (q == 0) osum[wv][c] = val;
    __syncthreads();
    if (wv == 0 && q == 0 && bb < B)
        out[bb] = osum[0][c] + osum[1][c] + b_fc[0];
}

extern "C" void kernel_launch(void* const* d_in, const int* in_sizes, int n_in,
                              void* d_out, int out_size, void* d_ws, size_t ws_size,
                              hipStream_t stream) {
    const float* x    = (const float*)d_in[0];
    const float* W_ih = (const float*)d_in[1];
    const float* W_hh = (const float*)d_in[2];
    const float* b_ih = (const float*)d_in[3];
    const float* b_hh = (const float*)d_in[4];
    const float* W_fc = (const float*)d_in[5];
    const float* b_fc = (const float*)d_in[6];
    float* out = (float*)d_out;
    const int B = in_sizes[0] / T_LEN;        // 4096
    dim3 block(128);                          // 2 waves = 16 batch elements
    dim3 grid((B + 15) / 16);                 // 256 blocks -> 2 SIMDs/CU
    reslstm_kernel<<<grid, block, 0, stream>>>(x, W_ih, W_hh, b_ih, b_hh,
                                               W_fc, b_fc, out, B);
}

// Round 20
// 239.576 us; speedup vs baseline: 1.3617x; 1.1639x over previous
//
#include <hip/hip_runtime.h>

// ResLSTM: B=4096, T=512, H=32.  ***R27 = R21 RESTORED (session best)***
// R21: 2 cooperating waves per 16 batches, MFMA K=32 recurrence,
//   raw-barrier h-exchange. Steady 183.7 us, absmax 9.8e-4.
//
// Why this is the final structure (session survey):
//   R7  341   LDS-broadcast VALU kernel (4 waves/SIMD floor)
//   R11 297   2-batch/wave, gates lane-local
//   R12 248   v_dot2_f32_f16 MAC          R14 230  rcp-fusion (trans 10->7)
//   R16 219   4-batch/wave = VALU-dot2 floor (32 dot2/batch fixed)
//   R18 305   MFMA K=16 1-wave  R19 279  K=32 (layout verified, MfmaUtil
//             halves exactly)   R20 197  2-wave split  R21 183.7 raw barrier
//   FAILED vs R21: R22 338 (2 groups in SAME wave: wall=2xbusy+stall);
//   R23 192.9 (4-wave: barrier cost scales with waves); R24 194.3 (K=16
//   split: 2x matrix-pipe occupancy at equal FLOPs); R25 267.9 (4 groups/
//   block: only 64 CUs usable -- parallelism capped at 512 waves = B/16
//   groups x 2 vs 1024 SIMDs); R26 225.4 (flag-poll sync: poll latency >
//   s_barrier; +0.8M bank conflicts).
//   Paper-rejected: fat/thin step alternation (fat step == R19's measured
//   1310cy), 32x32 tiles (halves wave count), batch-split (= R19).
// Remaining wall: strictly serial per-step chain MFMA -> GSTATE -> LDS
//   round-trip of a true recurrence at 1 wave/SIMD: ~560cy issue
//   (latency-inflated dependent chains) + ~64cy MFMA + ~240cy exchange.
//   Not a counter roofline; an exhaustively probed structural floor.

static constexpr int T_LEN = 512;
static constexpr int H = 32;

typedef _Float16 h2   __attribute__((ext_vector_type(2)));
typedef __fp16   fp2  __attribute__((ext_vector_type(2)));   // cvt_pkrtz type
typedef _Float16 v8h  __attribute__((ext_vector_type(8)));
typedef float    v4f  __attribute__((ext_vector_type(4)));

// D = A(8 f16) x B(8 f16) + C(4 f32), 16x16x32 f16 MFMA (K=32).
__device__ __forceinline__ v4f MF32(v8h a, v8h b, v4f c) {
#if __has_builtin(__builtin_amdgcn_mfma_f32_16x16x32_f16)
    return __builtin_amdgcn_mfma_f32_16x16x32_f16(a, b, c, 0, 0, 0);
#else
    v4f d = c;
    asm("v_mfma_f32_16x16x32_f16 %0, %1, %2, %0" : "+v"(d) : "v"(a), "v"(b));
    return d;
#endif
}

__device__ __forceinline__ v8h mkB(uint4 w) {
    union { uint4 u; v8h v; } u;
    u.u = w; return u.v;
}

__global__ void
__attribute__((amdgpu_flat_work_group_size(128, 128), amdgpu_waves_per_eu(1, 1)))
reslstm_kernel(const float* __restrict__ x,
               const float* __restrict__ W_ih,
               const float* __restrict__ W_hh,
               const float* __restrict__ b_ih,
               const float* __restrict__ b_hh,
               const float* __restrict__ W_fc,
               const float* __restrict__ b_fc,
               float* __restrict__ out, int B)
{
    // x chunk: [batch-col][t], pad 36.
    __shared__ float xl[16][36];
    // h exchange, double-buffered by step parity: [buf][q][c][wave] 8B.
    __shared__ uint2 hx[2][4][16][2];
    __shared__ float osum[2][16];

    const int tid  = threadIdx.x;
    const int lane = tid & 63;
    const int wv   = tid >> 6;           // wave 0: units 0-15, wave 1: 16-31
    const int c    = lane & 15;          // batch col (0..15)
    const int q    = lane >> 4;          // row quad  (0..3)

    const int wbase = blockIdx.x << 4;   // 16 batches per block
    if (wbase >= B) return;              // block-uniform guard
    const int bb = wbase + c;

    constexpr float NL2E  = -1.4426950408889634f;   // -log2(e)
    constexpr float N2L2E = 2.0f * NL2E;

    // A fragments: tile t = 2k + wv (gate k of unit-half wv).
    //   A8[k][m]   = Whh_sc[16t + c][4q + m]      (k-half 0)
    //   A8[k][4+m] = Whh_sc[16t + c][16 + 4q + m] (k-half 1)
    // Prescale: g gate (k==2) by 2*-log2(e), else -log2(e).
    v8h A8[4];
    v4f wih[4], bsb[4];
    #pragma unroll
    for (int k = 0; k < 4; ++k) {
        const int   t  = 2 * k + wv;
        const float sc = (k == 2) ? N2L2E : NL2E;
        const float4 w1 = *reinterpret_cast<const float4*>(
            W_hh + (16 * t + c) * H + 4 * q);
        const float4 w2 = *reinterpret_cast<const float4*>(
            W_hh + (16 * t + c) * H + 16 + 4 * q);
        A8[k][0] = (_Float16)(w1.x * sc); A8[k][1] = (_Float16)(w1.y * sc);
        A8[k][2] = (_Float16)(w1.z * sc); A8[k][3] = (_Float16)(w1.w * sc);
        A8[k][4] = (_Float16)(w2.x * sc); A8[k][5] = (_Float16)(w2.y * sc);
        A8[k][6] = (_Float16)(w2.z * sc); A8[k][7] = (_Float16)(w2.w * sc);
        const int r0 = 16 * t + 4 * q;
        const float4 wi = *reinterpret_cast<const float4*>(W_ih + r0);
        const float4 bi = *reinterpret_cast<const float4*>(b_ih + r0);
        const float4 bh = *reinterpret_cast<const float4*>(b_hh + r0);
        wih[k][0] = wi.x * sc; wih[k][1] = wi.y * sc;
        wih[k][2] = wi.z * sc; wih[k][3] = wi.w * sc;
        bsb[k][0] = (bi.x + bh.x) * sc; bsb[k][1] = (bi.y + bh.y) * sc;
        bsb[k][2] = (bi.z + bh.z) * sc; bsb[k][3] = (bi.w + bh.w) * sc;
    }

    // State: this wave's 4 units (16wv + 4q + m).
    float cs0 = 0.f, cs1 = 0.f, cs2 = 0.f, cs3 = 0.f;
    float hv0 = 0.f, hv1 = 0.f, hv2 = 0.f, hv3 = 0.f;
    v8h B8 = mkB(uint4{0u, 0u, 0u, 0u});          // h(0) = 0

// Light pins once per chunk (R6 lesson: asm outputs can't be rematerialized
// from memory -> weights stay VGPR-resident; R13: placement neutral).
#define PINALL()                                                              \
    asm volatile("" : "+v"(A8[0]), "+v"(A8[1]), "+v"(A8[2]), "+v"(A8[3]));    \
    asm volatile("" : "+v"(wih[0]), "+v"(wih[1]), "+v"(wih[2]), "+v"(wih[3]), \
                      "+v"(bsb[0]), "+v"(bsb[1]), "+v"(bsb[2]), "+v"(bsb[3]))

// R14 exp2 gate math (accums prescaled by -log2(e)):
//   c' = [c*Di*Dg + (1-Eg)*Df] * rcp(Df*Di*Dg);  h = (1-Ec) * rcp(Do*Dc).
#define GSTATE(AI, AF, AG, AO, CC, HH) do {                                   \
    const float Ei = __builtin_amdgcn_exp2f(AI);                              \
    const float Ef = __builtin_amdgcn_exp2f(AF);                              \
    const float Eg = __builtin_amdgcn_exp2f(AG);                              \
    const float Eo = __builtin_amdgcn_exp2f(AO);                              \
    const float Di = 1.0f + Ei, Df = 1.0f + Ef;                               \
    const float Dg = 1.0f + Eg, Do_ = 1.0f + Eo;                              \
    const float P  = Di * Dg;                                                 \
    const float t_ = (1.0f - Eg) * Df;                                        \
    const float u_ = __builtin_fmaf(CC, P, t_);                               \
    const float Rc = __builtin_amdgcn_rcpf(Df * P);                           \
    CC = u_ * Rc;                                                             \
    const float Ec = __builtin_amdgcn_exp2f(CC * N2L2E);                      \
    const float Dc = 1.0f + Ec;                                               \
    const float Rh = __builtin_amdgcn_rcpf(Do_ * Dc);                         \
    HH = (1.0f - Ec) * Rh;                                                    \
} while (0)

// One time step (this wave's half). PAR = step parity buffer (0/1).
// 4 MFMA -> 4 GSTATE (paired, each pair's h written as b32 ASAP) ->
// raw lgkmcnt+barrier -> b128 read of both halves -> B8 for next step.
// Race proof: read(t)[p] < own MFMA(t) < write(t+1)[1-p] < barrier(t+1)
// < other wave's write(t+2)[p].
#define STEP(XT, PAR) do {                                                    \
    const float xt = (XT);                                                    \
    v4f acc[4];                                                               \
    _Pragma("unroll")                                                         \
    for (int k = 0; k < 4; ++k) acc[k] = bsb[k] + wih[k] * xt;                \
    _Pragma("unroll")                                                         \
    for (int k = 0; k < 4; ++k) acc[k] = MF32(A8[k], B8, acc[k]);             \
    unsigned int* slot =                                                      \
        reinterpret_cast<unsigned int*>(&hx[PAR][q][c][wv]);                  \
    GSTATE(acc[0][0], acc[1][0], acc[2][0], acc[3][0], cs0, hv0);             \
    GSTATE(acc[0][1], acc[1][1], acc[2][1], acc[3][1], cs1, hv1);             \
    slot[0] = __builtin_bit_cast(unsigned int,                                \
                  __builtin_amdgcn_cvt_pkrtz(hv0, hv1));                      \
    GSTATE(acc[0][2], acc[1][2], acc[2][2], acc[3][2], cs2, hv2);             \
    GSTATE(acc[0][3], acc[1][3], acc[2][3], acc[3][3], cs3, hv3);             \
    slot[1] = __builtin_bit_cast(unsigned int,                                \
                  __builtin_amdgcn_cvt_pkrtz(hv2, hv3));                      \
    asm volatile("s_waitcnt lgkmcnt(0)\n\ts_barrier" ::: "memory");           \
    B8 = mkB(*reinterpret_cast<const uint4*>(&hx[PAR][q][c][0]));             \
} while (0)

    // x staging: thread tid owns row r=tid>>3, cols colb..colb+3 of chunk.
    const int r    = tid >> 3;
    const int colb = (tid & 7) << 2;
    const float* xsrc = x + (size_t)(wbase + r) * T_LEN + colb;
    float4 xA = *reinterpret_cast<const float4*>(xsrc);

    for (int tc = 0; tc < T_LEN / 32; ++tc) {
        PINALL();
        *reinterpret_cast<float4*>(&xl[r][colb]) = xA;
        __syncthreads();                  // stage visible to both waves
        if (tc + 1 < T_LEN / 32)
            xA = *reinterpret_cast<const float4*>(xsrc + (tc + 1) * 32);
        const float4* xq4c = reinterpret_cast<const float4*>(&xl[c][0]);
        #pragma unroll 2
        for (int t4 = 0; t4 < 8; ++t4) {
            const float4 xv = xq4c[t4];   // 4 steps of x in regs
            STEP(xv.x, 0);
            STEP(xv.y, 1);
            STEP(xv.z, 0);
            STEP(xv.w, 1);
        }
    }
#undef STEP
#undef GSTATE
#undef PINALL

    // out[bb] = sum_u h[u]*W_fc[u] + b_fc. This wave: units 16wv+4q+m.
    const int u0 = 16 * wv + 4 * q;
    float val = hv0 * W_fc[u0]     + hv1 * W_fc[u0 + 1]
              + hv2 * W_fc[u0 + 2] + hv3 * W_fc[u0 + 3];
    val += __shfl_xor(val, 16);
    val += __shfl_xor(val, 32);
    if (q == 0) osum[wv][c] = val;
    __syncthreads();
    if (wv == 0 && q == 0 && bb < B)
        out[bb] = osum[0][c] + osum[1][c] + b_fc[0];
}

extern "C" void kernel_launch(void* const* d_in, const int* in_sizes, int n_in,
                              void* d_out, int out_size, void* d_ws, size_t ws_size,
                              hipStream_t stream) {
    const float* x    = (const float*)d_in[0];
    const float* W_ih = (const float*)d_in[1];
    const float* W_hh = (const float*)d_in[2];
    const float* b_ih = (const float*)d_in[3];
    const float* b_hh = (const float*)d_in[4];
    const float* W_fc = (const float*)d_in[5];
    const float* b_fc = (const float*)d_in[6];
    float* out = (float*)d_out;
    const int B = in_sizes[0] / T_LEN;        // 4096
    dim3 block(128);                          // 2 waves = 16 batch elements
    dim3 grid((B + 15) / 16);                 // 256 blocks -> 2 SIMDs/CU
    reslstm_kernel<<<grid, block, 0, stream>>>(x, W_ih, W_hh, b_ih, b_hh,
                                               W_fc, b_fc, out, B);
}